// Round 3
// baseline (76.986 us; speedup 1.0000x reference)
//
#include <hip/hip_runtime.h>

// DistillKL 'w' branch forward, B=64, C=1000, T=4.
// loss = -(T^2/B) * sum_{b,i} max(p_t,1e-7) * max(expt*log(min(p_s,1)), log(1e-7))
// where p = exp(x) / (choice * neg_sum + exp(x)), x = y/4,
//   t3[i] = (1/C) sum_k w[k]*relu(x[i]-x[k]),
//   choice = w*exp(-t3) + (1-w), neg_sum = sum_k (1-w[k])*exp(x[k]),
//   expt  = w*min(|(pt1+1)/2 - ps1|,1)^0.25 + (1-w)*min(|pt1/2 - ps1|,1).
//
// v4: phase-2 is at its LDS/VALU pipe floor (~4 us); remaining controllable
// cost was dispatch count + serialization:
//  (a) distill_final fused in via last-block-done atomics (8-byte ws header
//      zeroed by a hipMemsetAsync graph node) -> one dispatch instead of two.
//  (b) compaction parallelized across all 8 waves (segment ballot + count
//      scan) instead of a serial wave-0 loop.

#define BN 64
#define CN 1000
#define CPAD 1024
#define SPLITS 8
#define CHUNK 125          // i-values per block (8*125 = 1000)
#define THREADS 512
#define NBLOCKS (BN * SPLITS)
#define NEG_LOG_EPS -16.118095650958319f   // log(1e-7)

__global__ __launch_bounds__(THREADS, 4) void distill_fused(
    const float* __restrict__ ys, const float* __restrict__ yt,
    const float* __restrict__ w, float* __restrict__ hdr,
    float* __restrict__ out)
{
    const int b = blockIdx.x;
    const int s = blockIdx.y;
    const int tid = threadIdx.x;
    const int lane = tid & 63;
    const int wid = tid >> 6;          // 8 waves per block

    __shared__ __align__(16) float xs[CPAD], xt[CPAD];     // x = y/4 (pad: 0)
    __shared__ __align__(16) float xsc[CPAD], xtc[CPAD];   // compacted positives (pad: 1e30)
    __shared__ float wsh[CPAD];                            // pad: 0
    __shared__ __align__(16) float ps0s[THREADS], ps1s[THREADS];  // slice partials, i0/i1
    __shared__ __align__(16) float ps0t[THREADS], ps1t[THREADS];
    __shared__ float redns[16];                            // 8 waves x 2 negsums
    __shared__ float redterm[2];
    __shared__ int segcnt[8];                              // per-wave positive counts

    const float* ysr = ys + b * CN;
    const float* ytr = yt + b * CN;
    const float* wr  = w  + b * CN;

    // Phase 1: stage x, w into LDS; accumulate neg_sum.
    float ns_s = 0.f, ns_t = 0.f;
    #pragma unroll
    for (int k = tid; k < CPAD; k += THREADS) {
        if (k < CN) {
            float a  = ysr[k] * 0.25f;
            float c2 = ytr[k] * 0.25f;
            float wk = wr[k];
            xs[k] = a; xt[k] = c2; wsh[k] = wk;
            float nw = 1.f - wk;
            ns_s += nw * expf(a);
            ns_t += nw * expf(c2);
        } else {
            xs[k] = 0.f; xt[k] = 0.f; wsh[k] = 0.f;
        }
    }
    #pragma unroll
    for (int off = 32; off > 0; off >>= 1) {
        ns_s += __shfl_down(ns_s, off);
        ns_t += __shfl_down(ns_t, off);
    }
    if (lane == 0) { redns[wid * 2] = ns_s; redns[wid * 2 + 1] = ns_t; }
    __syncthreads();
    float negsum_s = 0.f, negsum_t = 0.f;
    #pragma unroll
    for (int u = 0; u < 8; ++u) {
        negsum_s += redns[u * 2];
        negsum_t += redns[u * 2 + 1];
    }

    // Phase 1b: parallel compaction of positive-k list (ascending k),
    // padded to a multiple of 32 with +1e30 (relu contributes 0).
    // Wave `wid` owns k in [wid*128, wid*128+128).
    const int kA = wid * 128 + lane;
    const int kB = kA + 64;
    const bool posA = (wsh[kA] != 0.f);        // pad wsh==0 -> excluded
    const bool posB = (wsh[kB] != 0.f);
    const unsigned long long mA = __ballot(posA);
    const unsigned long long mB = __ballot(posB);
    const int cA = __popcll(mA);
    if (lane == 0) segcnt[wid] = cA + __popcll(mB);
    __syncthreads();
    int base = 0, tot = 0;
    #pragma unroll
    for (int u = 0; u < 8; ++u) {
        const int cu = segcnt[u];
        if (u < wid) base += cu;
        tot += cu;
    }
    const unsigned long long ltmask = (1ull << lane) - 1ull;
    if (posA) {
        const int d = base + __popcll(mA & ltmask);
        xsc[d] = xs[kA]; xtc[d] = xt[kA];
    }
    if (posB) {
        const int d = base + cA + __popcll(mB & ltmask);
        xsc[d] = xs[kB]; xtc[d] = xt[kB];
    }
    const int Mpad = (tot + 31) & ~31;
    for (int m = tot + tid; m < Mpad; m += THREADS) { xsc[m] = 1e30f; xtc[m] = 1e30f; }
    __syncthreads();

    // Phase 2: 64 i-slots x 8 k-slices; each thread handles 2 i's per float4.
    const int SL4 = Mpad >> 5;         // float4s per slice (Mpad/8/4), exact
    const int il = tid & 63;
    const int q  = tid >> 6;           // wave-uniform k-slice
    const int i0 = s * CHUNK + il;
    const bool has2 = (il < CHUNK - 64);   // il < 61
    const int i1 = has2 ? i0 + 64 : i0;
    const float xsi0 = xs[i0], xti0 = xt[i0];
    const float xsi1 = xs[i1], xti1 = xt[i1];
    const float4* s4 = reinterpret_cast<const float4*>(xsc) + q * SL4;
    const float4* t4 = reinterpret_cast<const float4*>(xtc) + q * SL4;
    float a0s = 0.f, a1s = 0.f, a0t = 0.f, a1t = 0.f;
    #pragma unroll 2
    for (int j = 0; j < SL4; ++j) {
        const float4 vs = s4[j];
        const float4 vt = t4[j];
        a0s += (fmaxf(xsi0 - vs.x, 0.f) + fmaxf(xsi0 - vs.y, 0.f))
             + (fmaxf(xsi0 - vs.z, 0.f) + fmaxf(xsi0 - vs.w, 0.f));
        a1s += (fmaxf(xsi1 - vs.x, 0.f) + fmaxf(xsi1 - vs.y, 0.f))
             + (fmaxf(xsi1 - vs.z, 0.f) + fmaxf(xsi1 - vs.w, 0.f));
        a0t += (fmaxf(xti0 - vt.x, 0.f) + fmaxf(xti0 - vt.y, 0.f))
             + (fmaxf(xti0 - vt.z, 0.f) + fmaxf(xti0 - vt.w, 0.f));
        a1t += (fmaxf(xti1 - vt.x, 0.f) + fmaxf(xti1 - vt.y, 0.f))
             + (fmaxf(xti1 - vt.z, 0.f) + fmaxf(xti1 - vt.w, 0.f));
    }
    ps0s[tid] = a0s; ps1s[tid] = a1s;
    ps0t[tid] = a0t; ps1t[tid] = a1t;
    __syncthreads();

    // Phase 3: threads 0..124 combine slice partials and compute the loss term.
    float term = 0.f;
    if (tid < CHUNK) {
        const int i = s * CHUNK + tid;
        const float* bs = (tid < 64) ? ps0s : ps1s;
        const float* bt = (tid < 64) ? ps0t : ps1t;
        const int off = tid & 63;
        float acc_s = 0.f, acc_t = 0.f;
        #pragma unroll
        for (int qq = 0; qq < 8; ++qq) {
            acc_s += bs[qq * 64 + off];
            acc_t += bt[qq * 64 + off];
        }
        const float t3s = acc_s * (1.0f / CN);
        const float t3t = acc_t * (1.0f / CN);
        const float wi = wsh[i];
        const float xsi = xs[i], xti = xt[i];
        const float ch_s = wi * expf(-t3s) + (1.f - wi);
        const float ch_t = wi * expf(-t3t) + (1.f - wi);
        const float exs = expf(xsi), ext = expf(xti);
        const float p_s = exs / (ch_s * negsum_s + exs);
        const float p_t = ext / (ch_t * negsum_t + ext);
        const float ps1 = fminf(p_s, 1.f);
        const float pt1 = fminf(p_t, 1.f);
        const float vpos = fminf(fabsf((pt1 + 1.f) * 0.5f - ps1), 1.f);
        const float vneg = fminf(fabsf(pt1 * 0.5f - ps1), 1.f);
        const float expt = wi * sqrtf(sqrtf(vpos)) + (1.f - wi) * vneg;
        const float logps = fmaxf(expt * logf(ps1), NEG_LOG_EPS);
        term = fmaxf(p_t, 1e-7f) * logps;
    }
    #pragma unroll
    for (int off = 32; off > 0; off >>= 1) term += __shfl_down(term, off);
    if (wid < 2 && lane == 0) redterm[wid] = term;
    __syncthreads();

    // Finalize: block partial -> device atomic; 512th block writes the loss.
    if (tid == 0) {
        const float bsum = redterm[0] + redterm[1];
        atomicAdd(&hdr[0], bsum);
        __threadfence();
        const unsigned old = atomicAdd(reinterpret_cast<unsigned*>(&hdr[1]), 1u);
        if (old == NBLOCKS - 1) {
            const float total = atomicAdd(&hdr[0], 0.0f);  // coherent read of full sum
            out[0] = -0.25f * total;                       // -(T*T)/B = -16/64
        }
    }
}

extern "C" void kernel_launch(void* const* d_in, const int* in_sizes, int n_in,
                              void* d_out, int out_size, void* d_ws, size_t ws_size,
                              hipStream_t stream) {
    const float* ys = (const float*)d_in[0];
    const float* yt = (const float*)d_in[1];
    const float* w  = (const float*)d_in[2];
    float* out = (float*)d_out;
    float* hdr = (float*)d_ws;   // [0]=fp32 accumulator, [1]=block counter

    hipMemsetAsync(hdr, 0, 8, stream);   // graph-capture-safe memset node
    dim3 grid(BN, SPLITS);
    distill_fused<<<grid, THREADS, 0, stream>>>(ys, yt, w, hdr, out);
}

// Round 4
// 67.797 us; speedup vs baseline: 1.1355x; 1.1355x over previous
//
#include <hip/hip_runtime.h>

// DistillKL 'w' branch forward, B=64, C=1000, T=4.
// loss = -(T^2/B) * sum_{b,i} max(p_t,1e-7) * max(expt*log(min(p_s,1)), log(1e-7))
// where p = exp(x) / (choice * neg_sum + exp(x)), x = y/4,
//   t3[i] = (1/C) sum_k w[k]*relu(x[i]-x[k]),
//   choice = w*exp(-t3) + (1-w), neg_sum = sum_k (1-w[k])*exp(x[k]),
//   expt  = w*min(|(pt1+1)/2 - ps1|,1)^0.25 + (1-w)*min(|pt1/2 - ps1|,1).
//
// v5: revert v4's fused atomics finalize (same-address atomic tail across
// 512 near-simultaneous blocks + launch-bounds(.,4) VGPR cap regressed +8.5us).
// Back to v3's verified two-kernel structure; keep v4's parallel compaction
// (all 8 waves, segment ballot + count scan) which is correct and removes
// the serial wave-0 loop. No min-waves launch bound.

#define BN 64
#define CN 1000
#define CPAD 1024
#define SPLITS 8
#define CHUNK 125          // i-values per block (8*125 = 1000)
#define THREADS 512
#define NEG_LOG_EPS -16.118095650958319f   // log(1e-7)

__global__ __launch_bounds__(THREADS) void distill_part(
    const float* __restrict__ ys, const float* __restrict__ yt,
    const float* __restrict__ w, float* __restrict__ part)
{
    const int b = blockIdx.x;
    const int s = blockIdx.y;
    const int tid = threadIdx.x;
    const int lane = tid & 63;
    const int wid = tid >> 6;          // 8 waves per block

    __shared__ __align__(16) float xs[CPAD], xt[CPAD];     // x = y/4 (pad: 0)
    __shared__ __align__(16) float xsc[CPAD], xtc[CPAD];   // compacted positives (pad: 1e30)
    __shared__ float wsh[CPAD];                            // pad: 0
    __shared__ __align__(16) float ps0s[THREADS], ps1s[THREADS];  // slice partials, i0/i1
    __shared__ __align__(16) float ps0t[THREADS], ps1t[THREADS];
    __shared__ float redns[16];                            // 8 waves x 2 negsums
    __shared__ float redterm[2];
    __shared__ int segcnt[8];                              // per-wave positive counts

    const float* ysr = ys + b * CN;
    const float* ytr = yt + b * CN;
    const float* wr  = w  + b * CN;

    // Phase 1: stage x, w into LDS; accumulate neg_sum.
    float ns_s = 0.f, ns_t = 0.f;
    #pragma unroll
    for (int k = tid; k < CPAD; k += THREADS) {
        if (k < CN) {
            float a  = ysr[k] * 0.25f;
            float c2 = ytr[k] * 0.25f;
            float wk = wr[k];
            xs[k] = a; xt[k] = c2; wsh[k] = wk;
            float nw = 1.f - wk;
            ns_s += nw * expf(a);
            ns_t += nw * expf(c2);
        } else {
            xs[k] = 0.f; xt[k] = 0.f; wsh[k] = 0.f;
        }
    }
    #pragma unroll
    for (int off = 32; off > 0; off >>= 1) {
        ns_s += __shfl_down(ns_s, off);
        ns_t += __shfl_down(ns_t, off);
    }
    if (lane == 0) { redns[wid * 2] = ns_s; redns[wid * 2 + 1] = ns_t; }
    __syncthreads();
    float negsum_s = 0.f, negsum_t = 0.f;
    #pragma unroll
    for (int u = 0; u < 8; ++u) {
        negsum_s += redns[u * 2];
        negsum_t += redns[u * 2 + 1];
    }

    // Phase 1b: parallel compaction of positive-k list (ascending k),
    // padded to a multiple of 32 with +1e30 (relu contributes 0).
    // Wave `wid` owns k in [wid*128, wid*128+128).
    const int kA = wid * 128 + lane;
    const int kB = kA + 64;
    const bool posA = (wsh[kA] != 0.f);        // pad wsh==0 -> excluded
    const bool posB = (wsh[kB] != 0.f);
    const unsigned long long mA = __ballot(posA);
    const unsigned long long mB = __ballot(posB);
    const int cA = __popcll(mA);
    if (lane == 0) segcnt[wid] = cA + __popcll(mB);
    __syncthreads();
    int base = 0, tot = 0;
    #pragma unroll
    for (int u = 0; u < 8; ++u) {
        const int cu = segcnt[u];
        if (u < wid) base += cu;
        tot += cu;
    }
    const unsigned long long ltmask = (1ull << lane) - 1ull;
    if (posA) {
        const int d = base + __popcll(mA & ltmask);
        xsc[d] = xs[kA]; xtc[d] = xt[kA];
    }
    if (posB) {
        const int d = base + cA + __popcll(mB & ltmask);
        xsc[d] = xs[kB]; xtc[d] = xt[kB];
    }
    const int Mpad = (tot + 31) & ~31;
    for (int m = tot + tid; m < Mpad; m += THREADS) { xsc[m] = 1e30f; xtc[m] = 1e30f; }
    __syncthreads();

    // Phase 2: 64 i-slots x 8 k-slices; each thread handles 2 i's per float4.
    const int SL4 = Mpad >> 5;         // float4s per slice (Mpad/8/4), exact
    const int il = tid & 63;
    const int q  = tid >> 6;           // wave-uniform k-slice
    const int i0 = s * CHUNK + il;
    const bool has2 = (il < CHUNK - 64);   // il < 61
    const int i1 = has2 ? i0 + 64 : i0;
    const float xsi0 = xs[i0], xti0 = xt[i0];
    const float xsi1 = xs[i1], xti1 = xt[i1];
    const float4* s4 = reinterpret_cast<const float4*>(xsc) + q * SL4;
    const float4* t4 = reinterpret_cast<const float4*>(xtc) + q * SL4;
    float a0s = 0.f, a1s = 0.f, a0t = 0.f, a1t = 0.f;
    #pragma unroll 2
    for (int j = 0; j < SL4; ++j) {
        const float4 vs = s4[j];
        const float4 vt = t4[j];
        a0s += (fmaxf(xsi0 - vs.x, 0.f) + fmaxf(xsi0 - vs.y, 0.f))
             + (fmaxf(xsi0 - vs.z, 0.f) + fmaxf(xsi0 - vs.w, 0.f));
        a1s += (fmaxf(xsi1 - vs.x, 0.f) + fmaxf(xsi1 - vs.y, 0.f))
             + (fmaxf(xsi1 - vs.z, 0.f) + fmaxf(xsi1 - vs.w, 0.f));
        a0t += (fmaxf(xti0 - vt.x, 0.f) + fmaxf(xti0 - vt.y, 0.f))
             + (fmaxf(xti0 - vt.z, 0.f) + fmaxf(xti0 - vt.w, 0.f));
        a1t += (fmaxf(xti1 - vt.x, 0.f) + fmaxf(xti1 - vt.y, 0.f))
             + (fmaxf(xti1 - vt.z, 0.f) + fmaxf(xti1 - vt.w, 0.f));
    }
    ps0s[tid] = a0s; ps1s[tid] = a1s;
    ps0t[tid] = a0t; ps1t[tid] = a1t;
    __syncthreads();

    // Phase 3: threads 0..124 combine slice partials and compute the loss term.
    float term = 0.f;
    if (tid < CHUNK) {
        const int i = s * CHUNK + tid;
        const float* bs = (tid < 64) ? ps0s : ps1s;
        const float* bt = (tid < 64) ? ps0t : ps1t;
        const int off = tid & 63;
        float acc_s = 0.f, acc_t = 0.f;
        #pragma unroll
        for (int qq = 0; qq < 8; ++qq) {
            acc_s += bs[qq * 64 + off];
            acc_t += bt[qq * 64 + off];
        }
        const float t3s = acc_s * (1.0f / CN);
        const float t3t = acc_t * (1.0f / CN);
        const float wi = wsh[i];
        const float xsi = xs[i], xti = xt[i];
        const float ch_s = wi * expf(-t3s) + (1.f - wi);
        const float ch_t = wi * expf(-t3t) + (1.f - wi);
        const float exs = expf(xsi), ext = expf(xti);
        const float p_s = exs / (ch_s * negsum_s + exs);
        const float p_t = ext / (ch_t * negsum_t + ext);
        const float ps1 = fminf(p_s, 1.f);
        const float pt1 = fminf(p_t, 1.f);
        const float vpos = fminf(fabsf((pt1 + 1.f) * 0.5f - ps1), 1.f);
        const float vneg = fminf(fabsf(pt1 * 0.5f - ps1), 1.f);
        const float expt = wi * sqrtf(sqrtf(vpos)) + (1.f - wi) * vneg;
        const float logps = fmaxf(expt * logf(ps1), NEG_LOG_EPS);
        term = fmaxf(p_t, 1e-7f) * logps;
    }
    #pragma unroll
    for (int off = 32; off > 0; off >>= 1) term += __shfl_down(term, off);
    if (wid < 2 && lane == 0) redterm[wid] = term;
    __syncthreads();
    if (tid == 0) part[b * SPLITS + s] = redterm[0] + redterm[1];
}

__global__ __launch_bounds__(64) void distill_final(
    const float* __restrict__ part, float* __restrict__ out)
{
    const int t = threadIdx.x;
    float v = 0.f;
    for (int j = t; j < BN * SPLITS; j += 64) v += part[j];
    #pragma unroll
    for (int off = 32; off > 0; off >>= 1) v += __shfl_down(v, off);
    if (t == 0) out[0] = -0.25f * v;    // -(T*T)/B = -16/64
}

extern "C" void kernel_launch(void* const* d_in, const int* in_sizes, int n_in,
                              void* d_out, int out_size, void* d_ws, size_t ws_size,
                              hipStream_t stream) {
    const float* ys = (const float*)d_in[0];
    const float* yt = (const float*)d_in[1];
    const float* w  = (const float*)d_in[2];
    float* out  = (float*)d_out;
    float* part = (float*)d_ws;   // BN*SPLITS floats

    dim3 grid(BN, SPLITS);
    distill_part<<<grid, THREADS, 0, stream>>>(ys, yt, w, part);
    distill_final<<<1, 64, 0, stream>>>(part, out);
}